// Round 1
// baseline (191.205 us; speedup 1.0000x reference)
//
#include <hip/hip_runtime.h>

// ONINorm: g=16 groups, n=128 rows/group, d=9216 cols, T=5 Newton-Schulz iters.
// Pipeline: center -> S=Zc*Zc^T -> normalize -> NS iterations -> W=B*Zc/sqrt(norm).

#define G 16
#define NROW 128
#define D 9216
#define OC 2048
#define KSPLIT 18
#define KCHUNK 512   // D / KSPLIT
#define EPSV 1e-5f

typedef float f32x16 __attribute__((ext_vector_type(16)));
typedef __bf16 bf16x8 __attribute__((ext_vector_type(8)));

union Frag {
    uint4 q;
    unsigned short s[8];
    bf16x8 v;
};

static __device__ __forceinline__ unsigned short f2bf(float x) {
    union { float f; unsigned int u; } a; a.f = x;
    unsigned int u = a.u;
    unsigned int r = u + 0x7FFFu + ((u >> 16) & 1u);   // RNE, inputs are finite
    return (unsigned short)(r >> 16);
}

static __device__ __forceinline__ float bf2f(unsigned short s) {
    union { unsigned int u; float f; } a; a.u = ((unsigned int)s) << 16;
    return a.f;
}

// Swizzled 128x128 bf16 matrix layout (element index). Granule = 8 elems = 16B.
// addr(r,c) = r*128 + ((c/8) ^ (r&15))*8 + c%8  -> frag reads are one ds_read_b128,
// rows r and r+16 share banks (2-way = free), others distinct.
static __device__ __forceinline__ int swz(int r, int c) {
    return (r << 7) + ((((c >> 3) ^ (r & 15)) << 3) | (c & 7));
}

// ---------------------------------------------------------------- K1: center
__global__ __launch_bounds__(256) void k_center(const float* __restrict__ W,
                                                unsigned short* __restrict__ Zc) {
    int row = blockIdx.x;
    int t = threadIdx.x;
    const float4* wp = (const float4*)(W + (size_t)row * D);
    float4 v[9];
    float s = 0.f;
#pragma unroll
    for (int i = 0; i < 9; i++) {
        v[i] = wp[t + i * 256];
        s += v[i].x + v[i].y + v[i].z + v[i].w;
    }
#pragma unroll
    for (int o = 32; o > 0; o >>= 1) s += __shfl_down(s, o, 64);
    __shared__ float ls[4];
    if ((t & 63) == 0) ls[t >> 6] = s;
    __syncthreads();
    float mean = (ls[0] + ls[1] + ls[2] + ls[3]) * (1.0f / 9216.0f);
    ushort4* zp = (ushort4*)(Zc + (size_t)row * D);
#pragma unroll
    for (int i = 0; i < 9; i++) {
        ushort4 o4;
        o4.x = f2bf(v[i].x - mean);
        o4.y = f2bf(v[i].y - mean);
        o4.z = f2bf(v[i].z - mean);
        o4.w = f2bf(v[i].w - mean);
        zp[t + i * 256] = o4;
    }
}

// ------------------------------------------------- K2: S partial GEMM (k-split)
// block (g, ks): S_part = Zc[:, chunk] * Zc[:, chunk]^T, both operands = same tile.
__global__ __launch_bounds__(256) void k_sgemm(const unsigned short* __restrict__ Zc,
                                               float* __restrict__ Spart) {
    __shared__ unsigned short tile[NROW * 128];
    int bid = blockIdx.x;
    int g = bid / KSPLIT, ks = bid % KSPLIT;
    int t = threadIdx.x, lane = t & 63, wave = t >> 6;
    int mq = (wave & 1) * 64, nq = (wave >> 1) * 64;
    int m = lane & 31, h = lane >> 5;

    f32x16 acc[2][2];
#pragma unroll
    for (int i = 0; i < 2; i++)
#pragma unroll
        for (int j = 0; j < 2; j++)
#pragma unroll
            for (int z = 0; z < 16; z++) acc[i][j][z] = 0.f;

    const unsigned short* zg = Zc + (size_t)g * NROW * D + ks * KCHUNK;

    for (int step = 0; step < 4; step++) {
        int dbase = step * 128;
        __syncthreads();
#pragma unroll
        for (int p = 0; p < 8; p++) {
            int flat = p * 256 + t;
            int r = flat >> 4, gc = flat & 15;
            uint4 dd = *(const uint4*)(zg + (size_t)r * D + dbase + gc * 8);
            *(uint4*)(tile + swz(r, gc * 8)) = dd;
        }
        __syncthreads();
#pragma unroll
        for (int kk = 0; kk < 8; kk++) {
            int kb = kk * 16 + h * 8;
            Frag a0, a1, b0, b1;
            a0.q = *(const uint4*)(tile + swz(mq + m, kb));
            a1.q = *(const uint4*)(tile + swz(mq + 32 + m, kb));
            b0.q = *(const uint4*)(tile + swz(nq + m, kb));
            b1.q = *(const uint4*)(tile + swz(nq + 32 + m, kb));
            acc[0][0] = __builtin_amdgcn_mfma_f32_32x32x16_bf16(a0.v, b0.v, acc[0][0], 0, 0, 0);
            acc[0][1] = __builtin_amdgcn_mfma_f32_32x32x16_bf16(a0.v, b1.v, acc[0][1], 0, 0, 0);
            acc[1][0] = __builtin_amdgcn_mfma_f32_32x32x16_bf16(a1.v, b0.v, acc[1][0], 0, 0, 0);
            acc[1][1] = __builtin_amdgcn_mfma_f32_32x32x16_bf16(a1.v, b1.v, acc[1][1], 0, 0, 0);
        }
    }
    float* sp = Spart + (size_t)(g * KSPLIT + ks) * 16384;
#pragma unroll
    for (int i = 0; i < 2; i++)
#pragma unroll
        for (int j = 0; j < 2; j++)
#pragma unroll
            for (int reg = 0; reg < 16; reg++) {
                int row = (reg & 3) + 8 * (reg >> 2) + 4 * h;
                sp[(mq + i * 32 + row) * 128 + nq + j * 32 + m] = acc[i][j][reg];
            }
}

// -------------------------------------- K3: reduce partials + eps*I + fro-norm acc
__global__ __launch_bounds__(256) void k_reduce(const float* __restrict__ Spart,
                                                float* __restrict__ Sred,
                                                float* __restrict__ normAcc) {
    int b = blockIdx.x;
    int g = b >> 4, part = b & 15;
    int el = part * 1024 + threadIdx.x * 4;
    float4 s = {0.f, 0.f, 0.f, 0.f};
    for (int ks = 0; ks < KSPLIT; ks++) {
        float4 p = *(const float4*)(Spart + (size_t)(g * KSPLIT + ks) * 16384 + el);
        s.x += p.x; s.y += p.y; s.z += p.z; s.w += p.w;
    }
    int r = el >> 7, c = el & 127;
    if (r >= c && r <= c + 3) {
        if (r == c) s.x += EPSV;
        else if (r == c + 1) s.y += EPSV;
        else if (r == c + 2) s.z += EPSV;
        else s.w += EPSV;
    }
    *(float4*)(Sred + (size_t)g * 16384 + el) = s;
    float sq = s.x * s.x + s.y * s.y + s.z * s.z + s.w * s.w;
#pragma unroll
    for (int o = 32; o > 0; o >>= 1) sq += __shfl_down(sq, o, 64);
    __shared__ float ls[4];
    if ((threadIdx.x & 63) == 0) ls[threadIdx.x >> 6] = sq;
    __syncthreads();
    if (threadIdx.x == 0) atomicAdd(normAcc + g, ls[0] + ls[1] + ls[2] + ls[3]);
}

// ------------------------------------------------ K4: Newton-Schulz (one blk/group)
// B1 = 1.5I - 0.5*Sn computed analytically (skips iteration 1), then 4 iterations:
//   phase1: U = B*B (bitwise symmetric -> stored transposed = itself),
//           V = B*Sn, stored transposed for use as MFMA B-operand.
//   phase2: B = 1.5*B - 0.5*U*V.
__global__ __launch_bounds__(512) void k_ns(const float* __restrict__ Sred,
                                            const float* __restrict__ normAcc,
                                            unsigned short* __restrict__ Bt) {
    extern __shared__ unsigned short sm[];
    unsigned short* Bb = sm;
    unsigned short* Sb = sm + 16384;
    unsigned short* Ub = sm + 32768;
    unsigned short* Vt = sm + 49152;
    int g = blockIdx.x;
    int t = threadIdx.x, lane = t & 63, wave = t >> 6;
    int m = lane & 31, h = lane >> 5;
    float rn = 1.0f / sqrtf(normAcc[g]);

    {   // init Sn (bf16) and B1 = 1.5I - 0.5*Sn
        int r = t >> 2, c0 = (t & 3) * 32;
        const float* sp = Sred + (size_t)g * 16384 + r * 128 + c0;
#pragma unroll
        for (int q = 0; q < 4; q++) {
            int c = c0 + q * 8;
            float4 x0 = *(const float4*)(sp + q * 8);
            float4 x1 = *(const float4*)(sp + q * 8 + 4);
            float vv[8] = {x0.x, x0.y, x0.z, x0.w, x1.x, x1.y, x1.z, x1.w};
            Frag fs, fb;
#pragma unroll
            for (int i = 0; i < 8; i++) {
                float sv = vv[i] * rn;
                fs.s[i] = f2bf(sv);
                float bv = -0.5f * sv + ((r == c + i) ? 1.5f : 0.f);
                fb.s[i] = f2bf(bv);
            }
            *(uint4*)(Sb + swz(r, c)) = fs.q;
            *(uint4*)(Bb + swz(r, c)) = fb.q;
        }
    }
    __syncthreads();

    for (int iter = 0; iter < 4; iter++) {
        // phase1: 32 tile-tasks (16 U + 16 V) over 8 waves
#pragma unroll
        for (int i = 0; i < 4; i++) {
            int task = wave * 4 + i;
            int tmb = ((task >> 2) & 3) * 32, tnb = (task & 3) * 32;
            const unsigned short* Bsrc = (task < 16) ? Bb : Sb;
            unsigned short* dst = (task < 16) ? Ub : Vt;
            f32x16 acc;
#pragma unroll
            for (int z = 0; z < 16; z++) acc[z] = 0.f;
#pragma unroll
            for (int kk = 0; kk < 8; kk++) {
                Frag a, bfr;
                a.q = *(const uint4*)(Bb + swz(tmb + m, kk * 16 + h * 8));
                bfr.q = *(const uint4*)(Bsrc + swz(tnb + m, kk * 16 + h * 8));
                acc = __builtin_amdgcn_mfma_f32_32x32x16_bf16(a.v, bfr.v, acc, 0, 0, 0);
            }
            // transposed packed store (4 consecutive rows share a granule)
#pragma unroll
            for (int q = 0; q < 4; q++) {
                union { unsigned short s[4]; uint2 u; } pk;
#pragma unroll
                for (int j = 0; j < 4; j++) pk.s[j] = f2bf(acc[q * 4 + j]);
                int rr = tmb + q * 8 + h * 4;
                int cc = tnb + m;
                *(uint2*)(dst + swz(cc, rr)) = pk.u;
            }
        }
        __syncthreads();
        // phase2: 16 tile-tasks, B = 1.5B - 0.5*U*V (in place, lane-owned elems)
#pragma unroll
        for (int i = 0; i < 2; i++) {
            int task = wave * 2 + i;
            int tmb = (task >> 2) * 32, tnb = (task & 3) * 32;
            f32x16 acc;
#pragma unroll
            for (int z = 0; z < 16; z++) acc[z] = 0.f;
#pragma unroll
            for (int kk = 0; kk < 8; kk++) {
                Frag a, bfr;
                a.q = *(const uint4*)(Ub + swz(tmb + m, kk * 16 + h * 8));
                bfr.q = *(const uint4*)(Vt + swz(tnb + m, kk * 16 + h * 8));
                acc = __builtin_amdgcn_mfma_f32_32x32x16_bf16(a.v, bfr.v, acc, 0, 0, 0);
            }
#pragma unroll
            for (int reg = 0; reg < 16; reg++) {
                int rr = tmb + (reg & 3) + 8 * (reg >> 2) + 4 * h;
                int cc = tnb + m;
                int e = swz(rr, cc);
                Bb[e] = f2bf(1.5f * bf2f(Bb[e]) - 0.5f * acc[reg]);
            }
        }
        __syncthreads();
    }
    {   // write B5 row-major bf16 to global
        int r = t >> 2, c0 = (t & 3) * 32;
        unsigned short* bp = Bt + (size_t)g * 16384 + r * 128;
#pragma unroll
        for (int q = 0; q < 4; q++) {
            uint4 dd = *(const uint4*)(Bb + swz(r, c0 + q * 8));
            *(uint4*)(bp + c0 + q * 8) = dd;
        }
    }
}

// -------------------------------------------- K5: W = (B5 * Zc) * norm^{-1/2}
__global__ __launch_bounds__(256) void k_wgemm(const unsigned short* __restrict__ Zc,
                                               const unsigned short* __restrict__ Bt,
                                               const float* __restrict__ normAcc,
                                               float* __restrict__ out) {
    __shared__ unsigned short Ab[16384];
    int nt = blockIdx.x, g = blockIdx.y;
    int t = threadIdx.x, lane = t & 63, wave = t >> 6;
    int m = lane & 31, h = lane >> 5;

    const unsigned short* bg = Bt + (size_t)g * 16384;
#pragma unroll
    for (int p = 0; p < 8; p++) {
        int flat = p * 256 + t;
        int r = flat >> 4, gc = flat & 15;
        uint4 dd = *(const uint4*)(bg + r * 128 + gc * 8);
        *(uint4*)(Ab + swz(r, gc * 8)) = dd;
    }
    __syncthreads();
    float ss = 1.0f / sqrtf(sqrtf(normAcc[g]));   // 1/sqrt(norm_S)

    int n0 = nt * 128 + wave * 32;
    const unsigned short* zg = Zc + (size_t)g * NROW * D + n0 + m;

    f32x16 acc[4];
#pragma unroll
    for (int i = 0; i < 4; i++)
#pragma unroll
        for (int z = 0; z < 16; z++) acc[i][z] = 0.f;

    Frag nxt;
#pragma unroll
    for (int j = 0; j < 8; j++) nxt.s[j] = zg[(size_t)(h * 8 + j) * D];
#pragma unroll
    for (int ks = 0; ks < 8; ks++) {
        Frag cur = nxt;
        if (ks < 7) {
#pragma unroll
            for (int j = 0; j < 8; j++)
                nxt.s[j] = zg[(size_t)((ks + 1) * 16 + h * 8 + j) * D];
        }
#pragma unroll
        for (int i = 0; i < 4; i++) {
            Frag a;
            a.q = *(const uint4*)(Ab + swz(i * 32 + m, ks * 16 + h * 8));
            acc[i] = __builtin_amdgcn_mfma_f32_32x32x16_bf16(a.v, cur.v, acc[i], 0, 0, 0);
        }
    }
    float* og = out + (size_t)(g * NROW) * D + n0 + m;
#pragma unroll
    for (int i = 0; i < 4; i++)
#pragma unroll
        for (int reg = 0; reg < 16; reg++) {
            int row = i * 32 + (reg & 3) + 8 * (reg >> 2) + 4 * h;
            og[(size_t)row * D] = acc[i][reg] * ss;
        }
}

// ------------------------------------------------------------------ launcher
extern "C" void kernel_launch(void* const* d_in, const int* in_sizes, int n_in,
                              void* d_out, int out_size, void* d_ws, size_t ws_size,
                              hipStream_t stream) {
    const float* W = (const float*)d_in[0];
    float* out = (float*)d_out;
    char* ws = (char*)d_ws;

    // ws layout (bytes): Zc bf16 [2048*9216]           @ 0        (37,748,736)
    //                    Spart f32 [16*18*128*128]     @ 37748736 (18,874,368)
    //                    Sred f32 [16*128*128]         @ 56623104 ( 1,048,576)
    //                    normAcc f32 [16]              @ 57671680 (64, padded)
    //                    Bt bf16 [16*128*128]          @ 57671744 (   524,288)
    unsigned short* Zc = (unsigned short*)(ws);
    float* Spart = (float*)(ws + 37748736ULL);
    float* Sred = (float*)(ws + 56623104ULL);
    float* normAcc = (float*)(ws + 57671680ULL);
    unsigned short* Bt = (unsigned short*)(ws + 57671744ULL);

    k_center<<<OC, 256, 0, stream>>>(W, Zc);
    k_sgemm<<<G * KSPLIT, 256, 0, stream>>>(Zc, Spart);
    hipMemsetAsync(normAcc, 0, 64, stream);
    k_reduce<<<256, 256, 0, stream>>>(Spart, Sred, normAcc);
    hipFuncSetAttribute((const void*)k_ns,
                        hipFuncAttributeMaxDynamicSharedMemorySize, 131072);
    k_ns<<<G, 512, 131072, stream>>>(Sred, normAcc, Bt);
    k_wgemm<<<dim3(72, G), 256, 0, stream>>>(Zc, Bt, normAcc, out);
}